// Round 4
// baseline (3150.693 us; speedup 1.0000x reference)
//
#include <hip/hip_runtime.h>
#include <math.h>
#include <stdint.h>

#define N_HEADS 4
#define N_NODES 10000
#define NPAD 10048           /* rounded up to multiple of TN */
#define EMB 128
#define N_BATCH 4096
#define NQ (2 * N_BATCH)     /* 8192 queries: [src(4096), dst(4096)] */
#define K 8
#define TQB 128              /* queries per block */
#define TN 64
#define NTILES (NPAD / TN)   /* 157 */
#define NSPLIT 2
#define TSPLIT 79            /* tiles in split 0; split 1 gets 78 */

typedef __attribute__((ext_vector_type(8))) __bf16 bf16x8;
typedef __attribute__((ext_vector_type(16))) float floatx16;

// ---------------------------------------------------------------------------
// helpers
// ---------------------------------------------------------------------------
__device__ __forceinline__ unsigned short f2bf(float x) {
  unsigned u = __float_as_uint(x);
  u += 0x7fff + ((u >> 16) & 1);           // round-to-nearest-even
  return (unsigned short)(u >> 16);
}
__device__ __forceinline__ float bf2f(unsigned short h) {
  return __uint_as_float(((unsigned)h) << 16);
}

// async global->LDS, 16B per lane; LDS dest = uniform base + lane*16
__device__ __forceinline__ void gload_lds16(const void* g, void* l) {
  __builtin_amdgcn_global_load_lds(
      (const __attribute__((address_space(1))) void*)g,
      (__attribute__((address_space(3))) void*)(uint32_t)(uintptr_t)l,
      16, 0, 0);
}

// sorted ascending top-8 insertion (tie-break: smaller node id)
__device__ __forceinline__ void insert8(float* bs, int* bi, float s, int node) {
  if (s < bs[K - 1] || (s == bs[K - 1] && node < bi[K - 1])) {
    #pragma unroll
    for (int k2 = K - 1; k2 >= 0; --k2) {
      bool better = (s < bs[k2]) || (s == bs[k2] && node < bi[k2]);
      if (!better) break;
      if (k2 < K - 1) { bs[k2 + 1] = bs[k2]; bi[k2 + 1] = bi[k2]; }
      bs[k2] = s; bi[k2] = node;
    }
  }
}

// ---------------------------------------------------------------------------
// Kernel P: split E into bf16 hi/lo (padded to NPAD rows) + squared norms.
// ---------------------------------------------------------------------------
__global__ __launch_bounds__(256) void prep_kernel(
    const float* __restrict__ E, unsigned short* __restrict__ Ehi,
    unsigned short* __restrict__ Elo, float* __restrict__ y2g) {
  int h = blockIdx.y;
  int n = blockIdx.x * 4 + (threadIdx.x >> 6);
  int lane = threadIdx.x & 63;
  float2 x = make_float2(0.f, 0.f);
  if (n < N_NODES)
    x = *(const float2*)(E + (size_t)(h * N_NODES + n) * EMB + 2 * lane);
  unsigned short h0 = f2bf(x.x), h1 = f2bf(x.y);
  unsigned short l0 = f2bf(x.x - bf2f(h0)), l1 = f2bf(x.y - bf2f(h1));
  size_t orow = (size_t)(h * NPAD + n) * EMB;
  ((ushort2*)(Ehi + orow))[lane] = make_ushort2(h0, h1);
  ((ushort2*)(Elo + orow))[lane] = make_ushort2(l0, l1);
  float s = x.x * x.x + x.y * x.y;
  #pragma unroll
  for (int o = 32; o > 0; o >>= 1) s += __shfl_xor(s, o);
  if (lane == 0) y2g[h * NPAD + n] = (n < N_NODES) ? s : 1e30f;
}

// ---------------------------------------------------------------------------
// Kernel A: MFMA knn. Grid (NQ/TQB=64, N_HEADS, NSPLIT=2). 8 waves (512 thr);
// wave (w0=wave>>1, w1=wave&1) owns the 32x32 tile at rows 32*w0, cols 32*w1
// of the 128x64 score tile. Query A-frags (hi+lo) in registers; node tiles
// stream through LDS via global_load_lds with the XOR-16 chunk swizzle
// applied on the GLOBAL source address (LDS side is lane-linear).
// Each split covers ~half the node range and emits sorted (score,node) top-8
// per query; merge_kernel folds the two splits.
// score = y2[n] - 2*dot (monotone in d2). Top-8 excluding self.
// ---------------------------------------------------------------------------
__global__ __launch_bounds__(512, 4) void knn_kernel(
    const unsigned short* __restrict__ Ehi, const unsigned short* __restrict__ Elo,
    const float* __restrict__ y2g, const int* __restrict__ be,
    float* __restrict__ candS, int* __restrict__ candI) {
  __shared__ __align__(16) unsigned short s_nhi[TN * EMB];  // 16 KiB
  __shared__ __align__(16) unsigned short s_nlo[TN * EMB];  // 16 KiB
  __shared__ __align__(16) float s_x[TQB * TN];             // 32 KiB: scores / q-staging
  __shared__ float s_ny2[TN];

  const int h = blockIdx.y, qt = blockIdx.x, sp = blockIdx.z;
  const int tid = threadIdx.x;
  const int wave = tid >> 6, lane = tid & 63;
  const int w0 = wave >> 1, w1 = wave & 1;
  const int lm = lane & 31, lh = lane >> 5;
  const int t0 = sp ? TSPLIT : 0;
  const int t1 = sp ? NTILES : TSPLIT;
  const unsigned short* EhiH = Ehi + (size_t)h * NPAD * EMB;
  const unsigned short* EloH = Elo + (size_t)h * NPAD * EMB;
  const float* y2H = y2g + h * NPAD;

  // ---- prologue: stage gathered query rows through s_x (swizzled), load A ----
  bf16x8 ahi[8], alo[8];
  unsigned short* s_xq = (unsigned short*)s_x;    // 128 rows x 128 ushort = 32 KiB
  {
    int r = tid >> 2, cbase = (tid & 3) * 4;      // 4 chunks of 8 ushort each
    int rx15 = r & 15;
    int q = be[qt * TQB + r];
    const int arow = 32 * w0 + lm;
    const int arx = arow & 15;
    const unsigned short* src = EhiH + (size_t)q * EMB;
    #pragma unroll
    for (int c = 0; c < 4; ++c) {
      int lc = cbase + c;
      *(bf16x8*)&s_xq[r * EMB + (lc ^ rx15) * 8] = *(const bf16x8*)&src[lc * 8];
    }
    __syncthreads();
    #pragma unroll
    for (int ks = 0; ks < 8; ++ks)
      ahi[ks] = *(const bf16x8*)&s_xq[arow * EMB + (((ks * 2 + lh) ^ arx)) * 8];
    __syncthreads();
    src = EloH + (size_t)q * EMB;
    #pragma unroll
    for (int c = 0; c < 4; ++c) {
      int lc = cbase + c;
      *(bf16x8*)&s_xq[r * EMB + (lc ^ rx15) * 8] = *(const bf16x8*)&src[lc * 8];
    }
    __syncthreads();
    #pragma unroll
    for (int ks = 0; ks < 8; ++ks)
      alo[ks] = *(const bf16x8*)&s_xq[arow * EMB + (((ks * 2 + lh) ^ arx)) * 8];
  }

  // selection state: 4 threads per query, each owns a 16-node column chunk
  const int qsel = tid >> 2;     // 0..127
  const int csel = tid & 3;
  const int myq = be[qt * TQB + qsel];
  float bs[K]; int bi[K];
  #pragma unroll
  for (int k2 = 0; k2 < K; ++k2) { bs[k2] = 1e30f; bi[k2] = 0x7fffffff; }

  for (int t = t0; t < t1; ++t) {
    __syncthreads();  // A: prev MFMA reads done; prev score writes visible
    {   // async staging of node tile t; source address carries the swizzle
      int nb = t * TN;
      #pragma unroll
      for (int it = 0; it < 2; ++it) {
        int q = it * 512 + wave * 64 + lane;   // chunk-linear index 0..1023
        int r = q >> 4;
        int c = (q ^ r) & 15;
        const unsigned short* sh = EhiH + (size_t)(nb + r) * EMB + c * 8;
        const unsigned short* sl = EloH + (size_t)(nb + r) * EMB + c * 8;
        gload_lds16(sh, s_nhi + (it * 512 + wave * 64) * 8);
        gload_lds16(sl, s_nlo + (it * 512 + wave * 64) * 8);
      }
      if (tid < TN) s_ny2[tid] = y2H[nb + tid];
    }
    if (t > t0) {  // selection on tile t-1's scores (bank-rotated scan)
      int nbp = (t - 1) * TN;
      #pragma unroll
      for (int s = 0; s < 16; ++s) {
        int j = csel * 16 + ((s + qsel) & 15);
        float sc = s_x[qsel * TN + j];
        int node = nbp + j;
        if (node == myq || node >= N_NODES) continue;
        insert8(bs, bi, sc, node);
      }
    }
    __syncthreads();  // B: staging complete (drains vmcnt), scores consumed

    floatx16 acc = {0.f, 0.f, 0.f, 0.f, 0.f, 0.f, 0.f, 0.f,
                    0.f, 0.f, 0.f, 0.f, 0.f, 0.f, 0.f, 0.f};
    const int brow = 32 * w1 + lm;
    const int brx = brow & 15;
    const unsigned short* nh = s_nhi + brow * EMB;
    const unsigned short* nl = s_nlo + brow * EMB;
    #pragma unroll
    for (int ks = 0; ks < 8; ++ks) {
      int pc = ((ks * 2 + lh) ^ brx) * 8;
      bf16x8 vbh = *(const bf16x8*)(nh + pc);
      bf16x8 vbl = *(const bf16x8*)(nl + pc);
      acc = __builtin_amdgcn_mfma_f32_32x32x16_bf16(alo[ks], vbh, acc, 0, 0, 0);
      acc = __builtin_amdgcn_mfma_f32_32x32x16_bf16(ahi[ks], vbl, acc, 0, 0, 0);
      acc = __builtin_amdgcn_mfma_f32_32x32x16_bf16(ahi[ks], vbh, acc, 0, 0, 0);
    }
    // scores -> s_x   (C/D layout: col=lane&31, row=(r&3)+8*(r>>2)+4*(lane>>5))
    float ny = s_ny2[brow & 31 + 32 * w1 - 32 * w1];  // = s_ny2[brow], brow<64
    ny = s_ny2[brow];
    #pragma unroll
    for (int r = 0; r < 16; ++r) {
      int row = (r & 3) + 8 * (r >> 2) + 4 * lh;
      s_x[(32 * w0 + row) * TN + 32 * w1 + lm] = fmaf(-2.f, acc[r], ny);
    }
  }

  // selection for the last tile
  __syncthreads();
  {
    int nbp = (t1 - 1) * TN;
    #pragma unroll
    for (int s = 0; s < 16; ++s) {
      int j = csel * 16 + ((s + qsel) & 15);
      float sc = s_x[qsel * TN + j];
      int node = nbp + j;
      if (node == myq || node >= N_NODES) continue;
      insert8(bs, bi, sc, node);
    }
  }
  // merge the 4 per-thread lists per query
  __syncthreads();
  float* ms = (float*)s_nhi;   // 512*8*4 = 16 KiB
  int*   mi = (int*)s_nlo;
  #pragma unroll
  for (int k2 = 0; k2 < K; ++k2) { ms[tid * 8 + k2] = bs[k2]; mi[tid * 8 + k2] = bi[k2]; }
  __syncthreads();
  if (tid < TQB) {
    float fs[K]; int fi[K];
    #pragma unroll
    for (int k2 = 0; k2 < K; ++k2) { fs[k2] = 1e30f; fi[k2] = 0x7fffffff; }
    for (int s = 0; s < 32; ++s) {
      int e = (s + tid) & 31;                    // bank-rotated scan
      insert8(fs, fi, ms[tid * 32 + e], mi[tid * 32 + e]);
    }
    size_t base = ((size_t)(h * NSPLIT + sp) * NQ + qt * TQB + tid) * K;
    #pragma unroll
    for (int k2 = 0; k2 < K; ++k2) {
      candS[base + k2] = fs[k2];
      candI[base + k2] = fi[k2];
    }
  }
}

// ---------------------------------------------------------------------------
// Kernel M: fold the two node-range splits into final top-8 indices.
// One thread per (head, query); both inputs are sorted ascending.
// ---------------------------------------------------------------------------
__global__ __launch_bounds__(256) void merge_kernel(
    const float* __restrict__ candS, const int* __restrict__ candI,
    int* __restrict__ samples) {
  int idx = blockIdx.x * 256 + threadIdx.x;   // h*NQ + q
  if (idx >= N_HEADS * NQ) return;
  int h = idx / NQ, q = idx - h * NQ;
  size_t bA = ((size_t)(h * NSPLIT + 0) * NQ + q) * K;
  size_t bB = ((size_t)(h * NSPLIT + 1) * NQ + q) * K;
  float fs[K]; int fi[K];
  #pragma unroll
  for (int k2 = 0; k2 < K; ++k2) { fs[k2] = 1e30f; fi[k2] = 0x7fffffff; }
  #pragma unroll
  for (int k2 = 0; k2 < K; ++k2) {
    insert8(fs, fi, candS[bA + k2], candI[bA + k2]);
    insert8(fs, fi, candS[bB + k2], candI[bB + k2]);
  }
  #pragma unroll
  for (int k2 = 0; k2 < K; ++k2) samples[(size_t)idx * K + k2] = fi[k2];
}

// ---------------------------------------------------------------------------
// Kernel B: epilogue (unchanged — verified absmax 0.0).
// ---------------------------------------------------------------------------
__global__ __launch_bounds__(256) void predict_kernel(
    const float* __restrict__ E, const float* __restrict__ F,
    const float* __restrict__ unc, const float* __restrict__ adj,
    const int* __restrict__ be, const int* __restrict__ samples,
    float* __restrict__ out) {
  int b = blockIdx.x;
  int h = threadIdx.x >> 6;
  int lane = threadIdx.x & 63;
  __shared__ float smv[N_HEADS];

  int srcb = be[b];
  int dstb = be[N_BATCH + b];
  const float* Eh = E + (size_t)h * N_NODES * EMB;
  const float* Fh = F + (size_t)h * N_NODES * EMB;
  float2 es = *(const float2*)(Eh + (size_t)srcb * EMB + 2 * lane);
  float2 ed = *(const float2*)(Eh + (size_t)dstb * EMB + 2 * lane);
  float2 fs = *(const float2*)(Fh + (size_t)srcb * EMB + 2 * lane);
  float2 fd = *(const float2*)(Fh + (size_t)dstb * EMB + 2 * lane);
  float u = unc[0];

  float logit[16], dist[16];
  #pragma unroll
  for (int j = 0; j < 16; ++j) {
    bool isrc = (j < 8);
    int qrow = isrc ? b : (N_BATCH + b);
    int s = samples[((size_t)h * NQ + qrow) * K + (j & 7)];
    float2 ev = *(const float2*)(Eh + (size_t)s * EMB + 2 * lane);
    float2 bb = isrc ? es : ed;
    float2 g = isrc ? fd : fs;
    float dx = bb.x - ev.x, dy = bb.y - ev.y;
    float dot = dx * g.x + dy * g.y;
    float nrm = dx * dx + dy * dy;
    #pragma unroll
    for (int o = 32; o > 0; o >>= 1) {
      dot += __shfl_xor(dot, o);
      nrm += __shfl_xor(nrm, o);
    }
    float a = isrc ? adj[(size_t)s * N_NODES + dstb]
                   : adj[(size_t)srcb * N_NODES + s];
    logit[j] = dot + u * (2.0f * a - 1.0f);
    dist[j] = sqrtf(nrm);
  }

  float m = 0.0f;  // sentinel: 1 - 1.0 = 0
  #pragma unroll
  for (int j = 0; j < 16; ++j) m = fmaxf(m, 1.0f - dist[j]);
  float Z = 8.0f * expf(-m);
  float num = 0.0f;
  #pragma unroll
  for (int j = 0; j < 16; ++j) {
    float e = expf(1.0f - dist[j] - m);
    Z += e;
    num += logit[j] * e;
  }
  if (lane == 0) smv[h] = num / Z;
  __syncthreads();
  if (threadIdx.x == 0) {
    float t = 0.25f * (smv[0] + smv[1] + smv[2] + smv[3]);
    out[b] = 1.0f / (1.0f + expf(-t));
  }
}

// ---------------------------------------------------------------------------
extern "C" void kernel_launch(void* const* d_in, const int* in_sizes, int n_in,
                              void* d_out, int out_size, void* d_ws,
                              size_t ws_size, hipStream_t stream) {
  const float* E = (const float*)d_in[0];
  const float* F = (const float*)d_in[1];
  const float* U = (const float*)d_in[2];
  const float* A = (const float*)d_in[3];
  const int* be = (const int*)d_in[4];
  float* out = (float*)d_out;

  // ws layout (256B-aligned):
  //   Ehi 10,289,152 | Elo 10,289,152 | y2g 160,768 | candS 2 MiB |
  //   candI 2 MiB | samples 1 MiB   (total ~26 MB)
  char* w = (char*)d_ws;
  unsigned short* Ehi = (unsigned short*)(w);
  unsigned short* Elo = (unsigned short*)(w + 10289152);
  float* y2g = (float*)(w + 2 * 10289152);
  float* candS = (float*)(w + 2 * 10289152 + 160768);
  int* candI = (int*)(w + 2 * 10289152 + 160768 + 2097152);
  int* samples = (int*)(w + 2 * 10289152 + 160768 + 2 * 2097152);

  prep_kernel<<<dim3(NPAD / 4, N_HEADS), 256, 0, stream>>>(E, Ehi, Elo, y2g);
  knn_kernel<<<dim3(NQ / TQB, N_HEADS, NSPLIT), 512, 0, stream>>>(
      Ehi, Elo, y2g, be, candS, candI);
  merge_kernel<<<dim3((N_HEADS * NQ + 255) / 256), 256, 0, stream>>>(
      candS, candI, samples);
  predict_kernel<<<dim3(N_BATCH), 256, 0, stream>>>(E, F, U, A, be, samples, out);
}

// Round 5
// 1228.235 us; speedup vs baseline: 2.5652x; 2.5652x over previous
//
#include <hip/hip_runtime.h>
#include <math.h>
#include <stdint.h>

#define N_HEADS 4
#define N_NODES 10000
#define NPAD 10048           /* rounded up to multiple of TN */
#define EMB 128
#define N_BATCH 4096
#define NQ (2 * N_BATCH)     /* 8192 queries: [src(4096), dst(4096)] */
#define K 8
#define TQ 64
#define TN 64
#define NTILES (NPAD / TN)   /* 157 */
#define NSPLIT 3
#define TSPL 53              /* tiles per split: 53,53,51 */

typedef __attribute__((ext_vector_type(8))) __bf16 bf16x8;
typedef __attribute__((ext_vector_type(16))) float floatx16;

// ---------------------------------------------------------------------------
// helpers
// ---------------------------------------------------------------------------
__device__ __forceinline__ unsigned short f2bf(float x) {
  unsigned u = __float_as_uint(x);
  u += 0x7fff + ((u >> 16) & 1);           // round-to-nearest-even
  return (unsigned short)(u >> 16);
}
__device__ __forceinline__ float bf2f(unsigned short h) {
  return __uint_as_float(((unsigned)h) << 16);
}

// async global->LDS, 16B per lane; LDS dest = uniform base + lane*16
__device__ __forceinline__ void gload_lds16(const void* g, void* l) {
  __builtin_amdgcn_global_load_lds(
      (const __attribute__((address_space(1))) void*)g,
      (__attribute__((address_space(3))) void*)(uint32_t)(uintptr_t)l,
      16, 0, 0);
}

// sorted ascending top-8 insertion (tie-break: smaller node id)
__device__ __forceinline__ void insert8(float* bs, int* bi, float s, int node) {
  if (s < bs[K - 1] || (s == bs[K - 1] && node < bi[K - 1])) {
    #pragma unroll
    for (int k2 = K - 1; k2 >= 0; --k2) {
      bool better = (s < bs[k2]) || (s == bs[k2] && node < bi[k2]);
      if (!better) break;
      if (k2 < K - 1) { bs[k2 + 1] = bs[k2]; bi[k2 + 1] = bi[k2]; }
      bs[k2] = s; bi[k2] = node;
    }
  }
}

// ---------------------------------------------------------------------------
// Kernel P: split E into bf16 hi/lo (padded to NPAD rows) + squared norms.
// ---------------------------------------------------------------------------
__global__ __launch_bounds__(256) void prep_kernel(
    const float* __restrict__ E, unsigned short* __restrict__ Ehi,
    unsigned short* __restrict__ Elo, float* __restrict__ y2g) {
  int h = blockIdx.y;
  int n = blockIdx.x * 4 + (threadIdx.x >> 6);
  int lane = threadIdx.x & 63;
  float2 x = make_float2(0.f, 0.f);
  if (n < N_NODES)
    x = *(const float2*)(E + (size_t)(h * N_NODES + n) * EMB + 2 * lane);
  unsigned short h0 = f2bf(x.x), h1 = f2bf(x.y);
  unsigned short l0 = f2bf(x.x - bf2f(h0)), l1 = f2bf(x.y - bf2f(h1));
  size_t orow = (size_t)(h * NPAD + n) * EMB;
  ((ushort2*)(Ehi + orow))[lane] = make_ushort2(h0, h1);
  ((ushort2*)(Elo + orow))[lane] = make_ushort2(l0, l1);
  float s = x.x * x.x + x.y * x.y;
  #pragma unroll
  for (int o = 32; o > 0; o >>= 1) s += __shfl_xor(s, o);
  if (lane == 0) y2g[h * NPAD + n] = (n < N_NODES) ? s : 1e30f;
}

// ---------------------------------------------------------------------------
// Kernel A: MFMA knn — R3 structure (256 thr, TQ=64, ~104 VGPR, no spill)
// + 3-way node-range split on blockIdx.z for occupancy/overlap.
// Grid (NQ/TQ=128, N_HEADS, NSPLIT). 4 waves; wave (w0,w1) owns the 32x32
// tile at rows 32*w0, cols 32*w1. Query A-frags (hi+lo) in registers; node
// tiles stream through LDS via global_load_lds with the XOR-16 chunk swizzle
// applied on the GLOBAL source address (LDS side is lane-linear).
// score = y2[n] - 2*dot (monotone in d2). Top-8 excluding self.
// ---------------------------------------------------------------------------
__global__ __launch_bounds__(256, 3) void knn_kernel(
    const unsigned short* __restrict__ Ehi, const unsigned short* __restrict__ Elo,
    const float* __restrict__ y2g, const int* __restrict__ be,
    float* __restrict__ candS, int* __restrict__ candI) {
  __shared__ __align__(16) unsigned short s_nhi[TN * EMB];  // 16 KiB
  __shared__ __align__(16) unsigned short s_nlo[TN * EMB];  // 16 KiB
  __shared__ __align__(16) float s_x[TQ * TN];              // 16 KiB: scores / q-staging
  __shared__ float s_ny2[TN];

  const int h = blockIdx.y, tile = blockIdx.x, sp = blockIdx.z;
  const int tid = threadIdx.x;
  const int wave = tid >> 6, lane = tid & 63;
  const int w0 = wave >> 1, w1 = wave & 1;
  const int lm = lane & 31, lh = lane >> 5;
  const int t0 = sp * TSPL;
  const int t1 = (sp == NSPLIT - 1) ? NTILES : (t0 + TSPL);
  const unsigned short* EhiH = Ehi + (size_t)h * NPAD * EMB;
  const unsigned short* EloH = Elo + (size_t)h * NPAD * EMB;
  const float* y2H = y2g + h * NPAD;

  // ---- prologue: stage gathered query rows through s_x (swizzled), load A ----
  bf16x8 ahi[8], alo[8];
  unsigned short* s_xq = (unsigned short*)s_x;
  {
    int r = tid >> 2, cbase = (tid & 3) * 4;    // 4 chunks of 8 ushort each
    int rx15 = r & 15;
    int q = be[tile * TQ + r];
    const int arow = 32 * w0 + lm;
    const int arx = arow & 15;
    const unsigned short* src = EhiH + (size_t)q * EMB;
    #pragma unroll
    for (int c = 0; c < 4; ++c) {
      int lc = cbase + c;
      *(bf16x8*)&s_xq[r * EMB + (lc ^ rx15) * 8] = *(const bf16x8*)&src[lc * 8];
    }
    __syncthreads();
    #pragma unroll
    for (int ks = 0; ks < 8; ++ks)
      ahi[ks] = *(const bf16x8*)&s_xq[arow * EMB + (((ks * 2 + lh) ^ arx)) * 8];
    __syncthreads();
    src = EloH + (size_t)q * EMB;
    #pragma unroll
    for (int c = 0; c < 4; ++c) {
      int lc = cbase + c;
      *(bf16x8*)&s_xq[r * EMB + (lc ^ rx15) * 8] = *(const bf16x8*)&src[lc * 8];
    }
    __syncthreads();
    #pragma unroll
    for (int ks = 0; ks < 8; ++ks)
      alo[ks] = *(const bf16x8*)&s_xq[arow * EMB + (((ks * 2 + lh) ^ arx)) * 8];
  }

  // selection state: 4 threads per query, each owns a 16-node column chunk
  const int qsel = tid >> 2;
  const int csel = tid & 3;
  const int myq = be[tile * TQ + qsel];
  float bs[K]; int bi[K];
  #pragma unroll
  for (int k2 = 0; k2 < K; ++k2) { bs[k2] = 1e30f; bi[k2] = 0x7fffffff; }

  for (int t = t0; t < t1; ++t) {
    __syncthreads();  // A: prev MFMA reads done; prev score writes visible
    {   // async staging of node tile t; source address carries the swizzle
      int nb = t * TN;
      #pragma unroll
      for (int it = 0; it < 4; ++it) {
        int q = wave * 256 + it * 64 + lane;   // chunk-linear index 0..1023
        int r = q >> 4;
        int c = (q ^ r) & 15;
        const unsigned short* sh = EhiH + (size_t)(nb + r) * EMB + c * 8;
        const unsigned short* sl = EloH + (size_t)(nb + r) * EMB + c * 8;
        gload_lds16(sh, s_nhi + wave * 2048 + it * 512);
        gload_lds16(sl, s_nlo + wave * 2048 + it * 512);
      }
      if (tid < TN) s_ny2[tid] = y2H[nb + tid];
    }
    if (t > t0) {  // selection on tile t-1's scores (bank-rotated scan)
      int nbp = (t - 1) * TN;
      #pragma unroll
      for (int s = 0; s < 16; ++s) {
        int j = csel * 16 + ((s + qsel) & 15);
        float sc = s_x[qsel * TN + j];
        int node = nbp + j;
        if (node == myq || node >= N_NODES) continue;
        insert8(bs, bi, sc, node);
      }
    }
    __syncthreads();  // B: staging complete (drains vmcnt), scores consumed

    floatx16 acc = {0.f, 0.f, 0.f, 0.f, 0.f, 0.f, 0.f, 0.f,
                    0.f, 0.f, 0.f, 0.f, 0.f, 0.f, 0.f, 0.f};
    const int brow = 32 * w1 + lm;
    const int brx = brow & 15;
    const unsigned short* nh = s_nhi + brow * EMB;
    const unsigned short* nl = s_nlo + brow * EMB;
    #pragma unroll
    for (int ks = 0; ks < 8; ++ks) {
      int pc = ((ks * 2 + lh) ^ brx) * 8;
      bf16x8 vbh = *(const bf16x8*)(nh + pc);
      bf16x8 vbl = *(const bf16x8*)(nl + pc);
      acc = __builtin_amdgcn_mfma_f32_32x32x16_bf16(alo[ks], vbh, acc, 0, 0, 0);
      acc = __builtin_amdgcn_mfma_f32_32x32x16_bf16(ahi[ks], vbl, acc, 0, 0, 0);
      acc = __builtin_amdgcn_mfma_f32_32x32x16_bf16(ahi[ks], vbh, acc, 0, 0, 0);
    }
    // scores -> s_x   (C/D layout: col=lane&31, row=(r&3)+8*(r>>2)+4*(lane>>5))
    float ny = s_ny2[brow];
    #pragma unroll
    for (int r = 0; r < 16; ++r) {
      int row = (r & 3) + 8 * (r >> 2) + 4 * lh;
      s_x[(32 * w0 + row) * TN + 32 * w1 + lm] = fmaf(-2.f, acc[r], ny);
    }
  }

  // selection for the last tile
  __syncthreads();
  {
    int nbp = (t1 - 1) * TN;
    #pragma unroll
    for (int s = 0; s < 16; ++s) {
      int j = csel * 16 + ((s + qsel) & 15);
      float sc = s_x[qsel * TN + j];
      int node = nbp + j;
      if (node == myq || node >= N_NODES) continue;
      insert8(bs, bi, sc, node);
    }
  }
  // merge the 4 per-thread lists per query
  __syncthreads();
  float* ms = (float*)s_nhi;   // 256*8*4 = 8 KiB
  int*   mi = (int*)s_nlo;
  #pragma unroll
  for (int k2 = 0; k2 < K; ++k2) { ms[tid * 8 + k2] = bs[k2]; mi[tid * 8 + k2] = bi[k2]; }
  __syncthreads();
  if (tid < TQ) {
    float fs[K]; int fi[K];
    #pragma unroll
    for (int k2 = 0; k2 < K; ++k2) { fs[k2] = 1e30f; fi[k2] = 0x7fffffff; }
    for (int s = 0; s < 32; ++s) {
      int e = (s + tid) & 31;                    // bank-rotated scan
      insert8(fs, fi, ms[tid * 32 + e], mi[tid * 32 + e]);
    }
    size_t base = ((size_t)(h * NSPLIT + sp) * NQ + tile * TQ + tid) * K;
    #pragma unroll
    for (int k2 = 0; k2 < K; ++k2) {
      candS[base + k2] = fs[k2];
      candI[base + k2] = fi[k2];
    }
  }
}

// ---------------------------------------------------------------------------
// Kernel M: fold the NSPLIT node-range splits into final top-8 indices.
// One thread per (head, query); inputs are sorted ascending.
// ---------------------------------------------------------------------------
__global__ __launch_bounds__(256) void merge_kernel(
    const float* __restrict__ candS, const int* __restrict__ candI,
    int* __restrict__ samples) {
  int idx = blockIdx.x * 256 + threadIdx.x;   // h*NQ + q
  if (idx >= N_HEADS * NQ) return;
  int h = idx / NQ, q = idx - h * NQ;
  float fs[K]; int fi[K];
  #pragma unroll
  for (int k2 = 0; k2 < K; ++k2) { fs[k2] = 1e30f; fi[k2] = 0x7fffffff; }
  #pragma unroll
  for (int sp = 0; sp < NSPLIT; ++sp) {
    size_t b = ((size_t)(h * NSPLIT + sp) * NQ + q) * K;
    #pragma unroll
    for (int k2 = 0; k2 < K; ++k2) insert8(fs, fi, candS[b + k2], candI[b + k2]);
  }
  #pragma unroll
  for (int k2 = 0; k2 < K; ++k2) samples[(size_t)idx * K + k2] = fi[k2];
}

// ---------------------------------------------------------------------------
// Kernel B: epilogue (unchanged — verified absmax 0.0).
// ---------------------------------------------------------------------------
__global__ __launch_bounds__(256) void predict_kernel(
    const float* __restrict__ E, const float* __restrict__ F,
    const float* __restrict__ unc, const float* __restrict__ adj,
    const int* __restrict__ be, const int* __restrict__ samples,
    float* __restrict__ out) {
  int b = blockIdx.x;
  int h = threadIdx.x >> 6;
  int lane = threadIdx.x & 63;
  __shared__ float smv[N_HEADS];

  int srcb = be[b];
  int dstb = be[N_BATCH + b];
  const float* Eh = E + (size_t)h * N_NODES * EMB;
  const float* Fh = F + (size_t)h * N_NODES * EMB;
  float2 es = *(const float2*)(Eh + (size_t)srcb * EMB + 2 * lane);
  float2 ed = *(const float2*)(Eh + (size_t)dstb * EMB + 2 * lane);
  float2 fs = *(const float2*)(Fh + (size_t)srcb * EMB + 2 * lane);
  float2 fd = *(const float2*)(Fh + (size_t)dstb * EMB + 2 * lane);
  float u = unc[0];

  float logit[16], dist[16];
  #pragma unroll
  for (int j = 0; j < 16; ++j) {
    bool isrc = (j < 8);
    int qrow = isrc ? b : (N_BATCH + b);
    int s = samples[((size_t)h * NQ + qrow) * K + (j & 7)];
    float2 ev = *(const float2*)(Eh + (size_t)s * EMB + 2 * lane);
    float2 bb = isrc ? es : ed;
    float2 g = isrc ? fd : fs;
    float dx = bb.x - ev.x, dy = bb.y - ev.y;
    float dot = dx * g.x + dy * g.y;
    float nrm = dx * dx + dy * dy;
    #pragma unroll
    for (int o = 32; o > 0; o >>= 1) {
      dot += __shfl_xor(dot, o);
      nrm += __shfl_xor(nrm, o);
    }
    float a = isrc ? adj[(size_t)s * N_NODES + dstb]
                   : adj[(size_t)srcb * N_NODES + s];
    logit[j] = dot + u * (2.0f * a - 1.0f);
    dist[j] = sqrtf(nrm);
  }

  float m = 0.0f;  // sentinel: 1 - 1.0 = 0
  #pragma unroll
  for (int j = 0; j < 16; ++j) m = fmaxf(m, 1.0f - dist[j]);
  float Z = 8.0f * expf(-m);
  float num = 0.0f;
  #pragma unroll
  for (int j = 0; j < 16; ++j) {
    float e = expf(1.0f - dist[j] - m);
    Z += e;
    num += logit[j] * e;
  }
  if (lane == 0) smv[h] = num / Z;
  __syncthreads();
  if (threadIdx.x == 0) {
    float t = 0.25f * (smv[0] + smv[1] + smv[2] + smv[3]);
    out[b] = 1.0f / (1.0f + expf(-t));
  }
}

// ---------------------------------------------------------------------------
extern "C" void kernel_launch(void* const* d_in, const int* in_sizes, int n_in,
                              void* d_out, int out_size, void* d_ws,
                              size_t ws_size, hipStream_t stream) {
  const float* E = (const float*)d_in[0];
  const float* F = (const float*)d_in[1];
  const float* U = (const float*)d_in[2];
  const float* A = (const float*)d_in[3];
  const int* be = (const int*)d_in[4];
  float* out = (float*)d_out;

  // ws layout (256B-aligned):
  //   Ehi 10,289,152 | Elo 10,289,152 | y2g 160,768 |
  //   candS 3,145,728 | candI 3,145,728 | samples 1,048,576  (~28.1 MB)
  char* w = (char*)d_ws;
  unsigned short* Ehi = (unsigned short*)(w);
  unsigned short* Elo = (unsigned short*)(w + 10289152);
  float* y2g = (float*)(w + 20578304);
  float* candS = (float*)(w + 20739072);
  int* candI = (int*)(w + 23884800);
  int* samples = (int*)(w + 27030528);

  prep_kernel<<<dim3(NPAD / 4, N_HEADS), 256, 0, stream>>>(E, Ehi, Elo, y2g);
  knn_kernel<<<dim3(NQ / TQ, N_HEADS, NSPLIT), 256, 0, stream>>>(
      Ehi, Elo, y2g, be, candS, candI);
  merge_kernel<<<dim3((N_HEADS * NQ + 255) / 256), 256, 0, stream>>>(
      candS, candI, samples);
  predict_kernel<<<dim3(N_BATCH), 256, 0, stream>>>(E, F, U, A, be, samples, out);
}

// Round 6
// 1072.189 us; speedup vs baseline: 2.9386x; 1.1455x over previous
//
#include <hip/hip_runtime.h>
#include <math.h>
#include <stdint.h>

#define N_HEADS 4
#define N_NODES 10000
#define NPAD 10048           /* rounded up to multiple of TN */
#define EMB 128
#define N_BATCH 4096
#define NQ (2 * N_BATCH)     /* 8192 queries: [src(4096), dst(4096)] */
#define K 8
#define TQ 64
#define TN 64
#define NTILES (NPAD / TN)   /* 157 */
#define NSPLIT 2
#define TSPL 79              /* tiles per split: 79, 78 */
#define PH1 4                /* warm-up tiles using private insert path */
#define CAP 25               /* per-query candidate list capacity (odd: bank-safe) */

typedef __attribute__((ext_vector_type(8))) __bf16 bf16x8;
typedef __attribute__((ext_vector_type(16))) float floatx16;

// ---------------------------------------------------------------------------
// helpers
// ---------------------------------------------------------------------------
__device__ __forceinline__ unsigned short f2bf(float x) {
  unsigned u = __float_as_uint(x);
  u += 0x7fff + ((u >> 16) & 1);           // round-to-nearest-even
  return (unsigned short)(u >> 16);
}
__device__ __forceinline__ float bf2f(unsigned short h) {
  return __uint_as_float(((unsigned)h) << 16);
}

// async global->LDS, 16B per lane; LDS dest = uniform base + lane*16
__device__ __forceinline__ void gload_lds16(const void* g, void* l) {
  __builtin_amdgcn_global_load_lds(
      (const __attribute__((address_space(1))) void*)g,
      (__attribute__((address_space(3))) void*)(uint32_t)(uintptr_t)l,
      16, 0, 0);
}

// sorted ascending top-8 insertion, no tie-break (ties measure-zero here)
__device__ __forceinline__ void insert8(float* bs, int* bi, float s, int node) {
  if (s < bs[K - 1]) {
    #pragma unroll
    for (int k2 = K - 1; k2 >= 0; --k2) {
      if (!(s < bs[k2])) break;
      if (k2 < K - 1) { bs[k2 + 1] = bs[k2]; bi[k2 + 1] = bi[k2]; }
      bs[k2] = s; bi[k2] = node;
    }
  }
}

// ---------------------------------------------------------------------------
// Kernel P: split E into bf16 hi/lo (padded to NPAD rows) + squared norms.
// ---------------------------------------------------------------------------
__global__ __launch_bounds__(256) void prep_kernel(
    const float* __restrict__ E, unsigned short* __restrict__ Ehi,
    unsigned short* __restrict__ Elo, float* __restrict__ y2g) {
  int h = blockIdx.y;
  int n = blockIdx.x * 4 + (threadIdx.x >> 6);
  int lane = threadIdx.x & 63;
  float2 x = make_float2(0.f, 0.f);
  if (n < N_NODES)
    x = *(const float2*)(E + (size_t)(h * N_NODES + n) * EMB + 2 * lane);
  unsigned short h0 = f2bf(x.x), h1 = f2bf(x.y);
  unsigned short l0 = f2bf(x.x - bf2f(h0)), l1 = f2bf(x.y - bf2f(h1));
  size_t orow = (size_t)(h * NPAD + n) * EMB;
  ((ushort2*)(Ehi + orow))[lane] = make_ushort2(h0, h1);
  ((ushort2*)(Elo + orow))[lane] = make_ushort2(l0, l1);
  float s = x.x * x.x + x.y * x.y;
  #pragma unroll
  for (int o = 32; o > 0; o >>= 1) s += __shfl_xor(s, o);
  if (lane == 0) y2g[h * NPAD + n] = (n < N_NODES) ? s : 1e30f;
}

// ---------------------------------------------------------------------------
// Kernel A: MFMA knn with filter-then-refine selection.
// Grid (NQ/TQ=128, N_HEADS, NSPLIT=2). 4 waves; wave (w0,w1) owns the 32x32
// MFMA tile at rows 32*w0, cols 32*w1. Query A-frags (hi+lo) in registers;
// node tiles stream through LDS via global_load_lds (XOR-16 chunk swizzle on
// the GLOBAL source address). score = y2[n] - 2*dot (monotone in d2).
//
// Selection: warm-up (PH1 tiles) -> private sorted top-8 per (query, 16-col
// stripe). Merge points (u = 4, 8, 16, 32, end): 64 threads fold privates +
// candidate list into per-query exact top-8 in LDS, set s_thr = 8th-best,
// reset list & privates. Steady state: per score a single compare vs s_thr;
// survivors (rare) append to the per-query list (LDS atomic); list overflow
// falls back to the private path. Self (node==query) filtered in slow paths.
// ---------------------------------------------------------------------------
__global__ __launch_bounds__(256, 2) void knn_kernel(
    const unsigned short* __restrict__ Ehi, const unsigned short* __restrict__ Elo,
    const float* __restrict__ y2g, const int* __restrict__ be,
    float* __restrict__ candS, int* __restrict__ candI) {
  __shared__ __align__(16) unsigned short s_nhi[TN * EMB];  // 16 KiB
  __shared__ __align__(16) unsigned short s_nlo[TN * EMB];  // 16 KiB
  __shared__ __align__(16) float s_x[TQ * TN];   // 16 KiB: q-staging / scores / merge scratch
  __shared__ float s_ny2[TN];
  __shared__ float s_thr[TQ];
  __shared__ int   s_cnt[TQ];
  __shared__ float s_t8S[TQ * 9];                // running top-8 (stride 9: bank-safe)
  __shared__ int   s_t8I[TQ * 9];
  __shared__ float s_lsS[TQ * CAP];              // candidate lists
  __shared__ int   s_lsI[TQ * CAP];

  const int h = blockIdx.y, tile = blockIdx.x, sp = blockIdx.z;
  const int tid = threadIdx.x;
  const int wave = tid >> 6, lane = tid & 63;
  const int w0 = wave >> 1, w1 = wave & 1;
  const int lm = lane & 31, lh = lane >> 5;
  const int t0 = sp * TSPL;
  const int t1 = sp ? NTILES : TSPL;
  const unsigned short* EhiH = Ehi + (size_t)h * NPAD * EMB;
  const unsigned short* EloH = Elo + (size_t)h * NPAD * EMB;
  const float* y2H = y2g + h * NPAD;

  // ---- prologue: stage gathered query rows through s_x (swizzled), load A ----
  bf16x8 ahi[8], alo[8];
  unsigned short* s_xq = (unsigned short*)s_x;
  {
    int r = tid >> 2, cbase = (tid & 3) * 4;    // 4 chunks of 8 ushort each
    int rx15 = r & 15;
    int q = be[tile * TQ + r];
    const int arow = 32 * w0 + lm;
    const int arx = arow & 15;
    const unsigned short* src = EhiH + (size_t)q * EMB;
    #pragma unroll
    for (int c = 0; c < 4; ++c) {
      int lc = cbase + c;
      *(bf16x8*)&s_xq[r * EMB + (lc ^ rx15) * 8] = *(const bf16x8*)&src[lc * 8];
    }
    __syncthreads();
    #pragma unroll
    for (int ks = 0; ks < 8; ++ks)
      ahi[ks] = *(const bf16x8*)&s_xq[arow * EMB + (((ks * 2 + lh) ^ arx)) * 8];
    __syncthreads();
    src = EloH + (size_t)q * EMB;
    #pragma unroll
    for (int c = 0; c < 4; ++c) {
      int lc = cbase + c;
      *(bf16x8*)&s_xq[r * EMB + (lc ^ rx15) * 8] = *(const bf16x8*)&src[lc * 8];
    }
    __syncthreads();
    #pragma unroll
    for (int ks = 0; ks < 8; ++ks)
      alo[ks] = *(const bf16x8*)&s_xq[arow * EMB + (((ks * 2 + lh) ^ arx)) * 8];
  }

  // selection state: 4 threads per query, each owns a 16-node column stripe
  const int qsel = tid >> 2;
  const int csel = tid & 3;
  const int myq = be[tile * TQ + qsel];
  float bs[K]; int bi[K];
  #pragma unroll
  for (int k2 = 0; k2 < K; ++k2) { bs[k2] = 1e30f; bi[k2] = 0x7fffffff; }
  if (tid < TQ) {
    s_cnt[tid] = 0;
    #pragma unroll
    for (int k2 = 0; k2 < K; ++k2) {
      s_t8S[tid * 9 + k2] = 1e30f; s_t8I[tid * 9 + k2] = 0x7fffffff;
    }
  }

  for (int t = t0; t < t1; ++t) {
    const int u = t - t0;
    __syncthreads();  // A: prev MFMA reads done; prev score writes visible
    {   // async staging of node tile t; source address carries the swizzle
      int nb = t * TN;
      #pragma unroll
      for (int it = 0; it < 4; ++it) {
        int qq = wave * 256 + it * 64 + lane;   // chunk-linear index 0..1023
        int r = qq >> 4;
        int c = (qq ^ r) & 15;
        gload_lds16(EhiH + (size_t)(nb + r) * EMB + c * 8, s_nhi + wave * 2048 + it * 512);
        gload_lds16(EloH + (size_t)(nb + r) * EMB + c * 8, s_nlo + wave * 2048 + it * 512);
      }
      if (tid < TN) s_ny2[tid] = y2H[nb + tid];
    }
    if (u > 0) {
      int nbp = (t - 1) * TN;
      if (u <= PH1) {            // warm-up: private sorted insert
        #pragma unroll
        for (int s = 0; s < 16; ++s) {
          int j = csel * 16 + ((s + qsel) & 15);
          float sc = s_x[qsel * TN + j];
          int node = nbp + j;
          if (node != myq) insert8(bs, bi, sc, node);
        }
      } else {                   // steady state: threshold filter + append
        float thr = s_thr[qsel];
        #pragma unroll
        for (int s = 0; s < 16; ++s) {
          int j = csel * 16 + ((s + qsel) & 15);
          float sc = s_x[qsel * TN + j];
          if (sc < thr) {
            int node = nbp + j;
            if (node != myq) {
              int p = atomicAdd(&s_cnt[qsel], 1);
              if (p < CAP) { s_lsS[qsel * CAP + p] = sc; s_lsI[qsel * CAP + p] = node; }
              else insert8(bs, bi, sc, node);   // overflow fallback
            }
          }
        }
      }
    }
    if (u == PH1 || u == 8 || u == 16 || u == 32) {   // merge point
      __syncthreads();                                 // M1: s_x reads done
      float* scrS = (float*)s_x;
      int*   scrI = (int*)s_x + TQ * 32;
      #pragma unroll
      for (int k2 = 0; k2 < K; ++k2) {
        scrS[tid * 8 + k2] = bs[k2]; scrI[tid * 8 + k2] = bi[k2];
        bs[k2] = 1e30f; bi[k2] = 0x7fffffff;
      }
      __syncthreads();                                 // M2: scratch visible
      if (tid < TQ) {
        int q = tid;
        int myqm = be[tile * TQ + q];
        float ts[K]; int ti[K];
        #pragma unroll
        for (int k2 = 0; k2 < K; ++k2) { ts[k2] = s_t8S[q * 9 + k2]; ti[k2] = s_t8I[q * 9 + k2]; }
        for (int kk = 0; kk < 32; ++kk) {
          int e = (kk + q) & 31;                       // bank-rotated scan
          float sv = scrS[q * 32 + e]; int iv = scrI[q * 32 + e];
          if (iv != myqm) insert8(ts, ti, sv, iv);
        }
        int cnt = s_cnt[q]; if (cnt > CAP) cnt = CAP;
        for (int p = 0; p < cnt; ++p) {
          float sv = s_lsS[q * CAP + p]; int iv = s_lsI[q * CAP + p];
          if (iv != myqm) insert8(ts, ti, sv, iv);
        }
        s_cnt[q] = 0;
        s_thr[q] = ts[K - 1];
        #pragma unroll
        for (int k2 = 0; k2 < K; ++k2) { s_t8S[q * 9 + k2] = ts[k2]; s_t8I[q * 9 + k2] = ti[k2]; }
      }
    }
    __syncthreads();  // B: staging drained; merge done; s_x free for epilogue

    floatx16 acc = {0.f, 0.f, 0.f, 0.f, 0.f, 0.f, 0.f, 0.f,
                    0.f, 0.f, 0.f, 0.f, 0.f, 0.f, 0.f, 0.f};
    const int brow = 32 * w1 + lm;
    const int brx = brow & 15;
    const unsigned short* nh = s_nhi + brow * EMB;
    const unsigned short* nl = s_nlo + brow * EMB;
    #pragma unroll
    for (int ks = 0; ks < 8; ++ks) {
      int pc = ((ks * 2 + lh) ^ brx) * 8;
      bf16x8 vbh = *(const bf16x8*)(nh + pc);
      bf16x8 vbl = *(const bf16x8*)(nl + pc);
      acc = __builtin_amdgcn_mfma_f32_32x32x16_bf16(alo[ks], vbh, acc, 0, 0, 0);
      acc = __builtin_amdgcn_mfma_f32_32x32x16_bf16(ahi[ks], vbl, acc, 0, 0, 0);
      acc = __builtin_amdgcn_mfma_f32_32x32x16_bf16(ahi[ks], vbh, acc, 0, 0, 0);
    }
    // scores -> s_x   (C/D layout: col=lane&31, row=(r&3)+8*(r>>2)+4*(lane>>5))
    float ny = s_ny2[brow];
    #pragma unroll
    for (int r = 0; r < 16; ++r) {
      int row = (r & 3) + 8 * (r >> 2) + 4 * lh;
      s_x[(32 * w0 + row) * TN + 32 * w1 + lm] = fmaf(-2.f, acc[r], ny);
    }
  }

  // ---- tail: select last tile's scores, then final merge + writeout ----
  __syncthreads();
  {
    int nbp = (t1 - 1) * TN;
    float thr = s_thr[qsel];
    #pragma unroll
    for (int s = 0; s < 16; ++s) {
      int j = csel * 16 + ((s + qsel) & 15);
      float sc = s_x[qsel * TN + j];
      if (sc < thr) {
        int node = nbp + j;
        if (node != myq) {
          int p = atomicAdd(&s_cnt[qsel], 1);
          if (p < CAP) { s_lsS[qsel * CAP + p] = sc; s_lsI[qsel * CAP + p] = node; }
          else insert8(bs, bi, sc, node);
        }
      }
    }
  }
  __syncthreads();
  {
    float* scrS = (float*)s_x;
    int*   scrI = (int*)s_x + TQ * 32;
    #pragma unroll
    for (int k2 = 0; k2 < K; ++k2) {
      scrS[tid * 8 + k2] = bs[k2]; scrI[tid * 8 + k2] = bi[k2];
    }
  }
  __syncthreads();
  if (tid < TQ) {
    float* scrS = (float*)s_x;
    int*   scrI = (int*)s_x + TQ * 32;
    int q = tid;
    int myqm = be[tile * TQ + q];
    float ts[K]; int ti[K];
    #pragma unroll
    for (int k2 = 0; k2 < K; ++k2) { ts[k2] = s_t8S[q * 9 + k2]; ti[k2] = s_t8I[q * 9 + k2]; }
    for (int kk = 0; kk < 32; ++kk) {
      int e = (kk + q) & 31;
      float sv = scrS[q * 32 + e]; int iv = scrI[q * 32 + e];
      if (iv != myqm) insert8(ts, ti, sv, iv);
    }
    int cnt = s_cnt[q]; if (cnt > CAP) cnt = CAP;
    for (int p = 0; p < cnt; ++p) {
      float sv = s_lsS[q * CAP + p]; int iv = s_lsI[q * CAP + p];
      if (iv != myqm) insert8(ts, ti, sv, iv);
    }
    size_t base = ((size_t)(h * NSPLIT + sp) * NQ + tile * TQ + q) * K;
    #pragma unroll
    for (int k2 = 0; k2 < K; ++k2) { candS[base + k2] = ts[k2]; candI[base + k2] = ti[k2]; }
  }
}

// ---------------------------------------------------------------------------
// Kernel M: fold the NSPLIT node-range splits into final top-8 indices.
// ---------------------------------------------------------------------------
__global__ __launch_bounds__(256) void merge_kernel(
    const float* __restrict__ candS, const int* __restrict__ candI,
    int* __restrict__ samples) {
  int idx = blockIdx.x * 256 + threadIdx.x;   // h*NQ + q
  if (idx >= N_HEADS * NQ) return;
  int h = idx / NQ, q = idx - h * NQ;
  float fs[K]; int fi[K];
  #pragma unroll
  for (int k2 = 0; k2 < K; ++k2) { fs[k2] = 1e30f; fi[k2] = 0x7fffffff; }
  #pragma unroll
  for (int sp = 0; sp < NSPLIT; ++sp) {
    size_t b = ((size_t)(h * NSPLIT + sp) * NQ + q) * K;
    #pragma unroll
    for (int k2 = 0; k2 < K; ++k2) insert8(fs, fi, candS[b + k2], candI[b + k2]);
  }
  #pragma unroll
  for (int k2 = 0; k2 < K; ++k2) samples[(size_t)idx * K + k2] = fi[k2];
}

// ---------------------------------------------------------------------------
// Kernel B: epilogue (unchanged — verified absmax 0.0).
// ---------------------------------------------------------------------------
__global__ __launch_bounds__(256) void predict_kernel(
    const float* __restrict__ E, const float* __restrict__ F,
    const float* __restrict__ unc, const float* __restrict__ adj,
    const int* __restrict__ be, const int* __restrict__ samples,
    float* __restrict__ out) {
  int b = blockIdx.x;
  int h = threadIdx.x >> 6;
  int lane = threadIdx.x & 63;
  __shared__ float smv[N_HEADS];

  int srcb = be[b];
  int dstb = be[N_BATCH + b];
  const float* Eh = E + (size_t)h * N_NODES * EMB;
  const float* Fh = F + (size_t)h * N_NODES * EMB;
  float2 es = *(const float2*)(Eh + (size_t)srcb * EMB + 2 * lane);
  float2 ed = *(const float2*)(Eh + (size_t)dstb * EMB + 2 * lane);
  float2 fs = *(const float2*)(Fh + (size_t)srcb * EMB + 2 * lane);
  float2 fd = *(const float2*)(Fh + (size_t)dstb * EMB + 2 * lane);
  float u = unc[0];

  float logit[16], dist[16];
  #pragma unroll
  for (int j = 0; j < 16; ++j) {
    bool isrc = (j < 8);
    int qrow = isrc ? b : (N_BATCH + b);
    int s = samples[((size_t)h * NQ + qrow) * K + (j & 7)];
    float2 ev = *(const float2*)(Eh + (size_t)s * EMB + 2 * lane);
    float2 bb = isrc ? es : ed;
    float2 g = isrc ? fd : fs;
    float dx = bb.x - ev.x, dy = bb.y - ev.y;
    float dot = dx * g.x + dy * g.y;
    float nrm = dx * dx + dy * dy;
    #pragma unroll
    for (int o = 32; o > 0; o >>= 1) {
      dot += __shfl_xor(dot, o);
      nrm += __shfl_xor(nrm, o);
    }
    float a = isrc ? adj[(size_t)s * N_NODES + dstb]
                   : adj[(size_t)srcb * N_NODES + s];
    logit[j] = dot + u * (2.0f * a - 1.0f);
    dist[j] = sqrtf(nrm);
  }

  float m = 0.0f;  // sentinel: 1 - 1.0 = 0
  #pragma unroll
  for (int j = 0; j < 16; ++j) m = fmaxf(m, 1.0f - dist[j]);
  float Z = 8.0f * expf(-m);
  float num = 0.0f;
  #pragma unroll
  for (int j = 0; j < 16; ++j) {
    float e = expf(1.0f - dist[j] - m);
    Z += e;
    num += logit[j] * e;
  }
  if (lane == 0) smv[h] = num / Z;
  __syncthreads();
  if (threadIdx.x == 0) {
    float t = 0.25f * (smv[0] + smv[1] + smv[2] + smv[3]);
    out[b] = 1.0f / (1.0f + expf(-t));
  }
}

// ---------------------------------------------------------------------------
extern "C" void kernel_launch(void* const* d_in, const int* in_sizes, int n_in,
                              void* d_out, int out_size, void* d_ws,
                              size_t ws_size, hipStream_t stream) {
  const float* E = (const float*)d_in[0];
  const float* F = (const float*)d_in[1];
  const float* U = (const float*)d_in[2];
  const float* A = (const float*)d_in[3];
  const int* be = (const int*)d_in[4];
  float* out = (float*)d_out;

  // ws layout (256B-aligned):
  //   Ehi 10,289,152 | Elo 10,289,152 | y2g 160,768 |
  //   candS 2,097,152 | candI 2,097,152 | samples 1,048,576  (~26 MB)
  char* w = (char*)d_ws;
  unsigned short* Ehi = (unsigned short*)(w);
  unsigned short* Elo = (unsigned short*)(w + 10289152);
  float* y2g = (float*)(w + 20578304);
  float* candS = (float*)(w + 20739072);
  int* candI = (int*)(w + 22836224);
  int* samples = (int*)(w + 24933376);

  prep_kernel<<<dim3(NPAD / 4, N_HEADS), 256, 0, stream>>>(E, Ehi, Elo, y2g);
  knn_kernel<<<dim3(NQ / TQ, N_HEADS, NSPLIT), 256, 0, stream>>>(
      Ehi, Elo, y2g, be, candS, candI);
  merge_kernel<<<dim3((N_HEADS * NQ + 255) / 256), 256, 0, stream>>>(
      candS, candI, samples);
  predict_kernel<<<dim3(N_BATCH), 256, 0, stream>>>(E, F, U, A, be, samples, out);
}